// Round 7
// baseline (296.825 us; speedup 1.0000x reference)
//
#include <hip/hip_runtime.h>

typedef unsigned short u16;
typedef unsigned int   u32;
typedef __attribute__((ext_vector_type(8)))  short short8;
typedef __attribute__((ext_vector_type(4)))  float f32x4v;

#define DEVI __device__ __forceinline__

constexpr int   Bb = 32, Nn = 4096, Dd = 256, Kk = 8, SDd = 64, HDd = 128;
constexpr float EPSc = 1e-8f, LNEPS = 1e-5f, SCALEc = 0.125f;  // SD^-0.5

DEVI u16 f2b(float f) {            // f32 -> bf16 RNE
  u32 u = __builtin_bit_cast(u32, f);
  return (u16)((u + 0x7fffu + ((u >> 16) & 1u)) >> 16);
}
DEVI float b2f(u16 s) { return __builtin_bit_cast(float, ((u32)s) << 16); }
DEVI float sigmoidf_(float x) { return 1.f / (1.f + __expf(-x)); }

DEVI void gll16(const void* g, void* l) {   // async 16B/lane global->LDS
  __builtin_amdgcn_global_load_lds(
      (const __attribute__((address_space(1))) u32*)g,
      (__attribute__((address_space(3))) u32*)l, 16, 0, 0);
}

DEVI float dot64(const float* __restrict__ a, const float* __restrict__ w) {
  float s = 0.f;
  #pragma unroll
  for (int i = 0; i < 16; ++i) {
    float4 av = *(const float4*)(a + i * 4);
    float4 wv = *(const float4*)(w + i * 4);
    s += av.x * wv.x + av.y * wv.y + av.z * wv.z + av.w * wv.w;
  }
  return s;
}
DEVI float dot128(const float* __restrict__ a, const float* __restrict__ w) {
  float s = 0.f;
  #pragma unroll
  for (int i = 0; i < 32; ++i) {
    float4 av = *(const float4*)(a + i * 4);
    float4 wv = *(const float4*)(w + i * 4);
    s += av.x * wv.x + av.y * wv.y + av.z * wv.z + av.w * wv.w;
  }
  return s;
}

// LayerNorm of 8 rows x 64 cols living in LDS (256 threads).
DEVI void ln8(const float* src, float* dst, const float* __restrict__ g,
              const float* __restrict__ b, int t) {
  int l = t & 63, w = t >> 6;
  int r = w * 2 + (l >> 5), c = l & 31;
  float x0 = src[r * 64 + c], x1 = src[r * 64 + c + 32];
  float s = x0 + x1, q2 = x0 * x0 + x1 * x1;
  #pragma unroll
  for (int m = 1; m < 32; m <<= 1) { s += __shfl_xor(s, m); q2 += __shfl_xor(q2, m); }
  float mean = s * (1.f / 64.f);
  float rs = rsqrtf(q2 * (1.f / 64.f) - mean * mean + LNEPS);
  dst[r * 64 + c]      = (x0 - mean) * rs * g[c]      + b[c];
  dst[r * 64 + c + 32] = (x1 - mean) * rs * g[c + 32] + b[c + 32];
}

// ---------------------------------------------------------------------------
// K0: weights -> bf16 swizzle images (consumed as MFMA B-fragments).
// ---------------------------------------------------------------------------
__global__ __launch_bounds__(256) void k_prep(
    const float* __restrict__ Wp, const float* __restrict__ Wk,
    const float* __restrict__ Wv, u16* __restrict__ wp_sw,
    u16* __restrict__ wk_sw, u16* __restrict__ wv_sw) {
  int i = blockIdx.x * 256 + threadIdx.x;
  if (i < 16384) wp_sw[i ^ (((i >> 8) & 7) << 3)] = f2b(Wp[i]);
  if (i < 4096) {
    wk_sw[i ^ (((i >> 6) & 7) << 3)] = f2b(Wk[i]);
    wv_sw[i ^ (((i >> 6) & 7) << 3)] = f2b(Wv[i]);
  }
}

// ---------------------------------------------------------------------------
// K1: fused LN(256) -> proj(256->64)+bias -> LN(64) -> k,v (64->64), bf16 out.
// (unchanged from R6 except k_ws layout: per-256-row swizzle image)
// ---------------------------------------------------------------------------
__global__ void k_proj_kv(
    const float* __restrict__ in, const float* __restrict__ gpro,
    const float* __restrict__ bpro, const u16* __restrict__ wp_sw,
    const float* __restrict__ bproj, const float* __restrict__ gin,
    const float* __restrict__ bin, const u16* __restrict__ wk_sw,
    const u16* __restrict__ wv_sw, u16* __restrict__ k_ws,
    u16* __restrict__ v_ws) {
  __shared__ float gp_l[256], bp_l[256];
  __shared__ __align__(16) u16 xn_lds[64 * 64];     // 8KB swizzled xn

  const int t = threadIdx.x, l = t & 63, w = t >> 6;
  const int r16 = l & 15, q4 = l >> 4;
  const long rowbase = (long)blockIdx.x * 64 + w * 16;
  const long grow = rowbase + r16;
  const float* rp = in + grow * 256;

  gp_l[t] = gpro[t];
  bp_l[t] = bpro[t];

  float4 x0[8], x1[8];
  #pragma unroll
  for (int ks = 0; ks < 8; ++ks) {
    x0[ks] = *(const float4*)(rp + ks * 32 + q4 * 8);
    x1[ks] = *(const float4*)(rp + ks * 32 + q4 * 8 + 4);
  }
  float sum = 0.f, sq = 0.f;
  #pragma unroll
  for (int ks = 0; ks < 8; ++ks) {
    sum += x0[ks].x + x0[ks].y + x0[ks].z + x0[ks].w +
           x1[ks].x + x1[ks].y + x1[ks].z + x1[ks].w;
    sq += x0[ks].x * x0[ks].x + x0[ks].y * x0[ks].y + x0[ks].z * x0[ks].z +
          x0[ks].w * x0[ks].w + x1[ks].x * x1[ks].x + x1[ks].y * x1[ks].y +
          x1[ks].z * x1[ks].z + x1[ks].w * x1[ks].w;
  }
  sum += __shfl_xor(sum, 16); sum += __shfl_xor(sum, 32);
  sq  += __shfl_xor(sq, 16);  sq  += __shfl_xor(sq, 32);
  float mean = sum * (1.f / 256.f);
  float rs = rsqrtf(sq * (1.f / 256.f) - mean * mean + LNEPS);
  __syncthreads();

  short8 a[8];
  #pragma unroll
  for (int ks = 0; ks < 8; ++ks) {
    int kb = ks * 32 + q4 * 8;
    a[ks][0] = (short)f2b((x0[ks].x - mean) * rs * gp_l[kb + 0] + bp_l[kb + 0]);
    a[ks][1] = (short)f2b((x0[ks].y - mean) * rs * gp_l[kb + 1] + bp_l[kb + 1]);
    a[ks][2] = (short)f2b((x0[ks].z - mean) * rs * gp_l[kb + 2] + bp_l[kb + 2]);
    a[ks][3] = (short)f2b((x0[ks].w - mean) * rs * gp_l[kb + 3] + bp_l[kb + 3]);
    a[ks][4] = (short)f2b((x1[ks].x - mean) * rs * gp_l[kb + 4] + bp_l[kb + 4]);
    a[ks][5] = (short)f2b((x1[ks].y - mean) * rs * gp_l[kb + 5] + bp_l[kb + 5]);
    a[ks][6] = (short)f2b((x1[ks].z - mean) * rs * gp_l[kb + 6] + bp_l[kb + 6]);
    a[ks][7] = (short)f2b((x1[ks].w - mean) * rs * gp_l[kb + 7] + bp_l[kb + 7]);
  }

  float bj4[4], gn4[4], bn4[4];
  #pragma unroll
  for (int nt = 0; nt < 4; ++nt) {
    int col = nt * 16 + r16;
    bj4[nt] = bproj[col]; gn4[nt] = gin[col]; bn4[nt] = bin[col];
  }

  f32x4v acc[4];
  #pragma unroll
  for (int nt = 0; nt < 4; ++nt)
    #pragma unroll
    for (int i = 0; i < 4; ++i) acc[nt][i] = 0.f;
  #define LDWP(ks, nt) \
    (*(const short8*)((const char*)wp_sw + \
        ((((nt) * 16 + r16) * 512 + 64 * (ks) + 16 * q4) ^ (((r16) & 7) << 4))))
  short8 b0 = LDWP(0, 0), b1 = LDWP(0, 1), b2f_ = LDWP(0, 2), b3 = LDWP(0, 3);
  #pragma unroll
  for (int ks = 0; ks < 8; ++ks) {
    short8 n0, n1, n2, n3;
    if (ks < 7) { n0 = LDWP(ks + 1, 0); n1 = LDWP(ks + 1, 1);
                  n2 = LDWP(ks + 1, 2); n3 = LDWP(ks + 1, 3); }
    acc[0] = __builtin_amdgcn_mfma_f32_16x16x32_bf16(a[ks], b0, acc[0], 0, 0, 0);
    acc[1] = __builtin_amdgcn_mfma_f32_16x16x32_bf16(a[ks], b1, acc[1], 0, 0, 0);
    acc[2] = __builtin_amdgcn_mfma_f32_16x16x32_bf16(a[ks], b2f_, acc[2], 0, 0, 0);
    acc[3] = __builtin_amdgcn_mfma_f32_16x16x32_bf16(a[ks], b3, acc[3], 0, 0, 0);
    b0 = n0; b1 = n1; b2f_ = n2; b3 = n3;
  }
  #undef LDWP
  #pragma unroll
  for (int nt = 0; nt < 4; ++nt)
    #pragma unroll
    for (int reg = 0; reg < 4; ++reg) acc[nt][reg] += bj4[nt];

  #pragma unroll
  for (int reg = 0; reg < 4; ++reg) {
    float s = acc[0][reg] + acc[1][reg] + acc[2][reg] + acc[3][reg];
    float q2 = acc[0][reg] * acc[0][reg] + acc[1][reg] * acc[1][reg] +
               acc[2][reg] * acc[2][reg] + acc[3][reg] * acc[3][reg];
    #pragma unroll
    for (int m = 1; m < 16; m <<= 1) { s += __shfl_xor(s, m); q2 += __shfl_xor(q2, m); }
    float mn = s * (1.f / 64.f);
    float rr = rsqrtf(q2 * (1.f / 64.f) - mn * mn + LNEPS);
    int row = q4 * 4 + reg;
    int rowg = w * 16 + row;
    #pragma unroll
    for (int nt = 0; nt < 4; ++nt) {
      int col = nt * 16 + r16;
      float y = (acc[nt][reg] - mn) * rr * gn4[nt] + bn4[nt];
      int byte = (rowg * 128 + 2 * col) ^ ((row & 7) << 4);
      *(u16*)((char*)xn_lds + byte) = f2b(y);
    }
  }

  f32x4v kacc[4], vacc[4];
  #pragma unroll
  for (int nt = 0; nt < 4; ++nt)
    #pragma unroll
    for (int i = 0; i < 4; ++i) { kacc[nt][i] = 0.f; vacc[nt][i] = 0.f; }
  #pragma unroll
  for (int ks = 0; ks < 2; ++ks) {
    int rowg2 = w * 16 + r16;
    short8 af = *(const short8*)((const char*)xn_lds +
                                 ((rowg2 * 128 + 64 * ks + 16 * q4) ^ ((r16 & 7) << 4)));
    #pragma unroll
    for (int nt = 0; nt < 4; ++nt) {
      int n = nt * 16 + r16;
      int wb = (n * 128 + 64 * ks + 16 * q4) ^ ((n & 7) << 4);
      short8 bk = *(const short8*)((const char*)wk_sw + wb);
      short8 bv = *(const short8*)((const char*)wv_sw + wb);
      kacc[nt] = __builtin_amdgcn_mfma_f32_16x16x32_bf16(af, bk, kacc[nt], 0, 0, 0);
      vacc[nt] = __builtin_amdgcn_mfma_f32_16x16x32_bf16(af, bv, vacc[nt], 0, 0, 0);
    }
  }
  #pragma unroll
  for (int nt = 0; nt < 4; ++nt) {
    #pragma unroll
    for (int reg = 0; reg < 4; ++reg) {
      int row = q4 * 4 + reg;
      long gr = rowbase + row;
      int col = nt * 16 + r16;
      long tile = gr >> 8;               // k: per-256-row swizzle image
      int  r    = (int)(gr & 255);
      long ko = tile * 16384 + ((r * 64 + col) ^ ((r & 7) << 3));
      k_ws[ko] = f2b(kacc[nt][reg]);
      v_ws[gr * 64 + col] = f2b(vacc[nt][reg]);
    }
  }
}

// ---------------------------------------------------------------------------
// K2: fused [optional GRU/MLP update prologue] + attention.
// grid (16, 32), 256 threads. Every block redundantly computes its batch's
// update (reads prev launch's U/S via kernel-boundary coherence); bx==0
// writes the slots. Then per-n logits/softmax; PV (iter mode) or attn-map
// write (final mode). k staged via gll16 from swizzle image (issued first).
// ---------------------------------------------------------------------------
__global__ __launch_bounds__(256) void k_attn_fused(
    const float* __restrict__ slots_prev,  // null -> init from noise
    const float* __restrict__ noise, const float* __restrict__ mu,
    const float* __restrict__ ls,
    const float* __restrict__ S_in, const float* __restrict__ U_in,  // null -> no update
    const float* __restrict__ W_ih, const float* __restrict__ W_hh,
    const float* __restrict__ b_ih, const float* __restrict__ b_hh,
    const float* __restrict__ gm, const float* __restrict__ bm,
    const float* __restrict__ W1, const float* __restrict__ b1,
    const float* __restrict__ W2, const float* __restrict__ b2,
    const float* __restrict__ gs, const float* __restrict__ bs,
    const float* __restrict__ Wq,
    const u16* __restrict__ k_sw, const u16* __restrict__ v_ws,
    float* __restrict__ S_out, float* __restrict__ U_out,
    float* __restrict__ slots_out,     // bx==0 writes (may be null)
    float* __restrict__ attn_out) {    // non-null -> final mode (no PV/U/S)
  const int bx = blockIdx.x, by = blockIdx.y, t = threadIdx.x;
  const int l = t & 63, w = t >> 6;
  __shared__ __align__(16) u16 k_l[16384];      // 32KB
  __shared__ float sp[512], u_l[512];
  __shared__ __align__(16) float gig[3072];     // gi|gh; reused as attn_l+sred
  __shared__ float sn2[512], mi[512], h1[1024], ql[512], Ssum[8];

  // issue k staging first (consumed after prologue; barrier drains vmcnt)
  {
    const char* gsrc = (const char*)(k_sw + ((long)(by * 16 + bx)) * 16384);
    #pragma unroll
    for (int i = 0; i < 8; ++i) {
      int off = i * 4096 + w * 1024 + l * 16;
      gll16(gsrc + off, (char*)k_l + off);
    }
  }

  // ---- prologue: slots_prev (or init) [+ GRU/MLP update] -> q in LDS ----
  for (int i = t; i < 512; i += 256) {
    float v;
    if (slots_prev) v = slots_prev[by * 512 + i];
    else { int d = i & 63; v = mu[d] + __expf(ls[d]) * noise[by * 512 + i]; }
    sp[i] = v;
  }
  const float* cur;
  if (S_in) {
    if (t < 8) {
      float s = 0.f;
      #pragma unroll
      for (int ch = 0; ch < 16; ++ch) s += S_in[(by * 16 + ch) * 8 + t];
      Ssum[t] = s;
    }
    __syncthreads();
    for (int i = t; i < 512; i += 256) {
      float s = 0.f;
      #pragma unroll
      for (int ch = 0; ch < 16; ++ch) s += U_in[((long)(by * 16 + ch)) * 512 + i];
      u_l[i] = s / (Ssum[i >> 6] + EPSc);
    }
    __syncthreads();
    float* gi = gig;
    float* gh = gig + 1536;
    for (int i = t; i < 1536; i += 256) {
      int kk = i / 192, j = i - kk * 192;
      gi[i] = b_ih[j] + dot64(u_l + kk * 64, W_ih + j * 64);
      gh[i] = b_hh[j] + dot64(sp + kk * 64, W_hh + j * 64);
    }
    __syncthreads();
    for (int i = t; i < 512; i += 256) {
      int kk = i >> 6, d = i & 63, base = kk * 192;
      float r = sigmoidf_(gi[base + d] + gh[base + d]);
      float z = sigmoidf_(gi[base + 64 + d] + gh[base + 64 + d]);
      float nn = tanhf(gi[base + 128 + d] + r * gh[base + 128 + d]);
      sn2[i] = (1.f - z) * nn + z * sp[i];
    }
    __syncthreads();
    ln8(sn2, mi, gm, bm, t);
    __syncthreads();
    for (int i = t; i < 1024; i += 256) {
      int kk = i >> 7, j = i & 127;
      h1[i] = fmaxf(b1[j] + dot64(mi + kk * 64, W1 + j * 64), 0.f);
    }
    __syncthreads();
    for (int i = t; i < 512; i += 256) {
      int kk = i >> 6, d = i & 63;
      float s = sn2[i] + b2[d] + dot128(h1 + kk * 128, W2 + d * 128);
      sn2[i] = s;
      if (slots_out && bx == 0) slots_out[by * 512 + i] = s;
    }
    cur = sn2;
  } else {
    cur = sp;
  }
  __syncthreads();
  ln8(cur, mi, gs, bs, t);
  __syncthreads();
  for (int i = t; i < 512; i += 256)
    ql[i] = SCALEc * dot64(mi + (i >> 6) * 64, Wq + (i & 63) * 64);
  __syncthreads();   // also guarantees k_l staged (vmcnt drained)

  // ---- logits for n = bx*256 + t (k from swizzled LDS) ----
  short8 kw8[8];
  #pragma unroll
  for (int j = 0; j < 8; ++j)
    kw8[j] = *(const short8*)((const char*)k_l + ((t * 128 + 16 * j) ^ ((t & 7) << 4)));
  float lg[8];
  #pragma unroll
  for (int i = 0; i < 8; ++i) lg[i] = 0.f;
  #pragma unroll
  for (int c4 = 0; c4 < 16; ++c4) {
    int j = c4 >> 1, e0 = (c4 & 1) * 4;
    float f0 = b2f((u16)kw8[j][e0]);
    float f1 = b2f((u16)kw8[j][e0 + 1]);
    float f2v = b2f((u16)kw8[j][e0 + 2]);
    float f3 = b2f((u16)kw8[j][e0 + 3]);
    #pragma unroll
    for (int kk = 0; kk < 8; ++kk) {
      float4 qv = *(const float4*)(ql + kk * 64 + c4 * 4);
      lg[kk] += qv.x * f0 + qv.y * f1 + qv.z * f2v + qv.w * f3;
    }
  }
  float mx = lg[0];
  #pragma unroll
  for (int kk = 1; kk < 8; ++kk) mx = fmaxf(mx, lg[kk]);
  float e[8], ss = 0.f;
  #pragma unroll
  for (int kk = 0; kk < 8; ++kk) { e[kk] = __expf(lg[kk] - mx); ss += e[kk]; }
  float inv = 1.f / ss;
  #pragma unroll
  for (int kk = 0; kk < 8; ++kk) e[kk] *= inv;

  if (attn_out) {   // final mode: write attention map, done
    int n = bx * 256 + t;
    #pragma unroll
    for (int kk = 0; kk < 8; ++kk)
      attn_out[((long)by * 8 + kk) * 4096 + n] = e[kk];
    return;
  }

  float* attn_l = gig;          // 2048 floats (prologue scratch dead)
  float* sred   = gig + 2048;
  float4 A0 = {e[0], e[1], e[2], e[3]}, A1 = {e[4], e[5], e[6], e[7]};
  *(float4*)(attn_l + t * 8) = A0;
  *(float4*)(attn_l + t * 8 + 4) = A1;
  __syncthreads();

  // ---- attn @ v : wave owns 64-n strip, lane owns d-pair; v dense direct ----
  float au[8][2];
  #pragma unroll
  for (int i = 0; i < 8; ++i) { au[i][0] = 0.f; au[i][1] = 0.f; }
  const int p = l & 31, g = l >> 5;
  const u32* vw = (const u32*)(v_ws + ((long)by * Nn + bx * 256 + w * 64) * 64);
  #pragma unroll 8
  for (int nn = 0; nn < 32; ++nn) {
    int n = nn * 2 + g;
    float4 a0 = *(const float4*)(attn_l + (w * 64 + n) * 8);
    float4 a1 = *(const float4*)(attn_l + (w * 64 + n) * 8 + 4);
    u32 vv = vw[n * 32 + p];
    float vlo = b2f((u16)(vv & 0xffff)), vhi = b2f((u16)(vv >> 16));
    au[0][0] += a0.x * vlo; au[0][1] += a0.x * vhi;
    au[1][0] += a0.y * vlo; au[1][1] += a0.y * vhi;
    au[2][0] += a0.z * vlo; au[2][1] += a0.z * vhi;
    au[3][0] += a0.w * vlo; au[3][1] += a0.w * vhi;
    au[4][0] += a1.x * vlo; au[4][1] += a1.x * vhi;
    au[5][0] += a1.y * vlo; au[5][1] += a1.y * vhi;
    au[6][0] += a1.z * vlo; au[6][1] += a1.z * vhi;
    au[7][0] += a1.w * vlo; au[7][1] += a1.w * vhi;
  }
  #pragma unroll
  for (int kk = 0; kk < 8; ++kk) {
    au[kk][0] += __shfl_xor(au[kk][0], 32);
    au[kk][1] += __shfl_xor(au[kk][1], 32);
  }
  float s8[8];
  #pragma unroll
  for (int kk = 0; kk < 8; ++kk) {
    s8[kk] = e[kk];
    #pragma unroll
    for (int m = 1; m < 64; m <<= 1) s8[kk] += __shfl_xor(s8[kk], m);
  }
  __syncthreads();            // attn_l reads done -> reuse as ured
  float* ured = attn_l;
  if (l < 32) {
    #pragma unroll
    for (int kk = 0; kk < 8; ++kk) {
      ured[w * 512 + kk * 64 + 2 * p]     = au[kk][0];
      ured[w * 512 + kk * 64 + 2 * p + 1] = au[kk][1];
    }
  }
  if (l == 0) {
    #pragma unroll
    for (int kk = 0; kk < 8; ++kk) sred[w * 8 + kk] = s8[kk];
  }
  __syncthreads();
  for (int i = t; i < 512; i += 256)
    U_out[((long)(by * 16 + bx)) * 512 + i] =
        ured[i] + ured[512 + i] + ured[1024 + i] + ured[1536 + i];
  if (t < 8)
    S_out[(by * 16 + bx) * 8 + t] = sred[t] + sred[8 + t] + sred[16 + t] + sred[24 + t];
}

extern "C" void kernel_launch(void* const* d_in, const int* in_sizes, int n_in,
                              void* d_out, int out_size, void* d_ws, size_t ws_size,
                              hipStream_t stream) {
  (void)in_sizes; (void)n_in; (void)out_size; (void)ws_size;
  const float* in    = (const float*)d_in[0];
  const float* noise = (const float*)d_in[1];
  const float* mu    = (const float*)d_in[2];
  const float* ls    = (const float*)d_in[3];
  const float* gpro  = (const float*)d_in[4];
  const float* bpro  = (const float*)d_in[5];
  const float* Wp    = (const float*)d_in[6];
  const float* bproj = (const float*)d_in[7];
  const float* Wq    = (const float*)d_in[8];
  const float* Wk    = (const float*)d_in[9];
  const float* Wv    = (const float*)d_in[10];
  const float* W_ih  = (const float*)d_in[11];
  const float* W_hh  = (const float*)d_in[12];
  const float* b_ih  = (const float*)d_in[13];
  const float* b_hh  = (const float*)d_in[14];
  const float* W1    = (const float*)d_in[15];
  const float* b1    = (const float*)d_in[16];
  const float* W2    = (const float*)d_in[17];
  const float* b2    = (const float*)d_in[18];
  const float* gin   = (const float*)d_in[19];
  const float* bin   = (const float*)d_in[20];
  const float* gs    = (const float*)d_in[21];
  const float* bs    = (const float*)d_in[22];
  const float* gm    = (const float*)d_in[23];
  const float* bm    = (const float*)d_in[24];

  char* ws = (char*)d_ws;
  u16* k_ws      = (u16*)ws;                                   // 16 MiB swizzle image
  u16* v_ws      = (u16*)(ws + 16777216);                      // 16 MiB linear
  float* S_a     = (float*)(ws + 33554432);                    // 16 KiB
  float* S_b     = (float*)(ws + 33554432 + 16384);            // 16 KiB
  float* U_a     = (float*)(ws + 33554432 + 32768);            // 1 MiB
  float* U_b     = (float*)(ws + 33554432 + 32768 + 1048576);  // 1 MiB
  float* slots1  = (float*)(ws + 33554432 + 32768 + 2097152);  // 64 KiB
  float* slots2  = (float*)(ws + 33554432 + 32768 + 2097152 + 65536);
  u16* wp_sw     = (u16*)(ws + 33554432 + 32768 + 2097152 + 131072);
  u16* wk_sw     = wp_sw + 16384;
  u16* wv_sw     = wk_sw + 4096;
  float* out = (float*)d_out;

  k_prep<<<dim3(64), dim3(256), 0, stream>>>(Wp, Wk, Wv, wp_sw, wk_sw, wv_sw);
  k_proj_kv<<<dim3(2048), dim3(256), 0, stream>>>(in, gpro, bpro, wp_sw, bproj,
                                                  gin, bin, wk_sw, wv_sw, k_ws, v_ws);
  dim3 g2(16, 32), blk(256);
  // iter 0: slots = init(noise); no update prologue; writes S_a/U_a
  k_attn_fused<<<g2, blk, 0, stream>>>(nullptr, noise, mu, ls, nullptr, nullptr,
                                       W_ih, W_hh, b_ih, b_hh, gm, bm, W1, b1, W2,
                                       b2, gs, bs, Wq, k_ws, v_ws, S_a, U_a,
                                       nullptr, nullptr);
  // iter 1: prologue update0 (S_a/U_a, prev=init); writes slots1, S_b/U_b
  k_attn_fused<<<g2, blk, 0, stream>>>(nullptr, noise, mu, ls, S_a, U_a,
                                       W_ih, W_hh, b_ih, b_hh, gm, bm, W1, b1, W2,
                                       b2, gs, bs, Wq, k_ws, v_ws, S_b, U_b,
                                       slots1, nullptr);
  // iter 2: prologue update1 (S_b/U_b, prev=slots1); writes slots2, S_a/U_a
  k_attn_fused<<<g2, blk, 0, stream>>>(slots1, noise, mu, ls, S_b, U_b,
                                       W_ih, W_hh, b_ih, b_hh, gm, bm, W1, b1, W2,
                                       b2, gs, bs, Wq, k_ws, v_ws, S_a, U_a,
                                       slots2, nullptr);
  // final: prologue update2 (S_a/U_a, prev=slots2) -> slots to d_out; attn map
  k_attn_fused<<<g2, blk, 0, stream>>>(slots2, noise, mu, ls, S_a, U_a,
                                       W_ih, W_hh, b_ih, b_hh, gm, bm, W1, b1, W2,
                                       b2, gs, bs, Wq, k_ws, v_ws, nullptr, nullptr,
                                       out, out + 16384);
}

// Round 8
// 241.682 us; speedup vs baseline: 1.2282x; 1.2282x over previous
//
#include <hip/hip_runtime.h>

typedef unsigned short u16;
typedef unsigned int   u32;
typedef __attribute__((ext_vector_type(8)))  short short8;
typedef __attribute__((ext_vector_type(4)))  float f32x4v;

#define DEVI __device__ __forceinline__

constexpr int   Bb = 32, Nn = 4096, Dd = 256, Kk = 8, SDd = 64, HDd = 128;
constexpr float EPSc = 1e-8f, LNEPS = 1e-5f, SCALEc = 0.125f;  // SD^-0.5

DEVI u16 f2b(float f) {            // f32 -> bf16 RNE
  u32 u = __builtin_bit_cast(u32, f);
  return (u16)((u + 0x7fffu + ((u >> 16) & 1u)) >> 16);
}
DEVI float b2f(u16 s) { return __builtin_bit_cast(float, ((u32)s) << 16); }
DEVI float sigmoidf_(float x) { return 1.f / (1.f + __expf(-x)); }

DEVI void gll16(const void* g, void* l) {   // async 16B/lane global->LDS
  __builtin_amdgcn_global_load_lds(
      (const __attribute__((address_space(1))) u32*)g,
      (__attribute__((address_space(3))) u32*)l, 16, 0, 0);
}

DEVI float dot64(const float* __restrict__ a, const float* __restrict__ w) {
  float s = 0.f;
  #pragma unroll
  for (int i = 0; i < 16; ++i) {
    float4 av = *(const float4*)(a + i * 4);
    float4 wv = *(const float4*)(w + i * 4);
    s += av.x * wv.x + av.y * wv.y + av.z * wv.z + av.w * wv.w;
  }
  return s;
}
DEVI float dot128(const float* __restrict__ a, const float* __restrict__ w) {
  float s = 0.f;
  #pragma unroll
  for (int i = 0; i < 32; ++i) {
    float4 av = *(const float4*)(a + i * 4);
    float4 wv = *(const float4*)(w + i * 4);
    s += av.x * wv.x + av.y * wv.y + av.z * wv.z + av.w * wv.w;
  }
  return s;
}

// LayerNorm of 8 rows x 64 cols living in LDS (256 threads).
DEVI void ln8(const float* src, float* dst, const float* __restrict__ g,
              const float* __restrict__ b, int t) {
  int l = t & 63, w = t >> 6;
  int r = w * 2 + (l >> 5), c = l & 31;
  float x0 = src[r * 64 + c], x1 = src[r * 64 + c + 32];
  float s = x0 + x1, q2 = x0 * x0 + x1 * x1;
  #pragma unroll
  for (int m = 1; m < 32; m <<= 1) { s += __shfl_xor(s, m); q2 += __shfl_xor(q2, m); }
  float mean = s * (1.f / 64.f);
  float rs = rsqrtf(q2 * (1.f / 64.f) - mean * mean + LNEPS);
  dst[r * 64 + c]      = (x0 - mean) * rs * g[c]      + b[c];
  dst[r * 64 + c + 32] = (x1 - mean) * rs * g[c + 32] + b[c + 32];
}

// ---------------------------------------------------------------------------
// K0: blocks 0..63: weights -> bf16 swizzle images.
//     blocks 64..95: initial slots -> LN -> q (batch = blk-64) into q_ws.
// ---------------------------------------------------------------------------
__global__ __launch_bounds__(256) void k_prep(
    const float* __restrict__ Wp, const float* __restrict__ Wk,
    const float* __restrict__ Wv, u16* __restrict__ wp_sw,
    u16* __restrict__ wk_sw, u16* __restrict__ wv_sw,
    const float* __restrict__ noise, const float* __restrict__ mu,
    const float* __restrict__ ls, const float* __restrict__ gs,
    const float* __restrict__ bs, const float* __restrict__ Wq,
    float* __restrict__ q_ws) {
  const int t = threadIdx.x;
  if (blockIdx.x < 64) {
    int i = blockIdx.x * 256 + t;
    if (i < 16384) wp_sw[i ^ (((i >> 8) & 7) << 3)] = f2b(Wp[i]);
    if (i < 4096) {
      wk_sw[i ^ (((i >> 6) & 7) << 3)] = f2b(Wk[i]);
      wv_sw[i ^ (((i >> 6) & 7) << 3)] = f2b(Wv[i]);
    }
    return;
  }
  const int b = blockIdx.x - 64;
  __shared__ float sl[512], snl[512];
  for (int i = t; i < 512; i += 256) {
    int d = i & 63;
    sl[i] = mu[d] + __expf(ls[d]) * noise[b * 512 + i];
  }
  __syncthreads();
  ln8(sl, snl, gs, bs, t);
  __syncthreads();
  for (int i = t; i < 512; i += 256)
    q_ws[b * 512 + i] = SCALEc * dot64(snl + (i >> 6) * 64, Wq + (i & 63) * 64);
}

// ---------------------------------------------------------------------------
// K1: fused LN(256) -> proj(256->64)+bias -> LN(64) -> k,v (64->64), bf16.
// R6 structure (A-frag strided loads, dbuf B-frags from global images,
// 10KB LDS). k_ws: per-128-row swizzle image; v_ws linear.
// ---------------------------------------------------------------------------
__global__ void k_proj_kv(
    const float* __restrict__ in, const float* __restrict__ gpro,
    const float* __restrict__ bpro, const u16* __restrict__ wp_sw,
    const float* __restrict__ bproj, const float* __restrict__ gin,
    const float* __restrict__ bin, const u16* __restrict__ wk_sw,
    const u16* __restrict__ wv_sw, u16* __restrict__ k_ws,
    u16* __restrict__ v_ws) {
  __shared__ float gp_l[256], bp_l[256];
  __shared__ __align__(16) u16 xn_lds[64 * 64];     // 8KB swizzled xn

  const int t = threadIdx.x, l = t & 63, w = t >> 6;
  const int r16 = l & 15, q4 = l >> 4;
  const long rowbase = (long)blockIdx.x * 64 + w * 16;
  const long grow = rowbase + r16;
  const float* rp = in + grow * 256;

  gp_l[t] = gpro[t];
  bp_l[t] = bpro[t];

  float4 x0[8], x1[8];
  #pragma unroll
  for (int ks = 0; ks < 8; ++ks) {
    x0[ks] = *(const float4*)(rp + ks * 32 + q4 * 8);
    x1[ks] = *(const float4*)(rp + ks * 32 + q4 * 8 + 4);
  }
  float sum = 0.f, sq = 0.f;
  #pragma unroll
  for (int ks = 0; ks < 8; ++ks) {
    sum += x0[ks].x + x0[ks].y + x0[ks].z + x0[ks].w +
           x1[ks].x + x1[ks].y + x1[ks].z + x1[ks].w;
    sq += x0[ks].x * x0[ks].x + x0[ks].y * x0[ks].y + x0[ks].z * x0[ks].z +
          x0[ks].w * x0[ks].w + x1[ks].x * x1[ks].x + x1[ks].y * x1[ks].y +
          x1[ks].z * x1[ks].z + x1[ks].w * x1[ks].w;
  }
  sum += __shfl_xor(sum, 16); sum += __shfl_xor(sum, 32);
  sq  += __shfl_xor(sq, 16);  sq  += __shfl_xor(sq, 32);
  float mean = sum * (1.f / 256.f);
  float rs = rsqrtf(sq * (1.f / 256.f) - mean * mean + LNEPS);
  __syncthreads();

  short8 a[8];
  #pragma unroll
  for (int ks = 0; ks < 8; ++ks) {
    int kb = ks * 32 + q4 * 8;
    a[ks][0] = (short)f2b((x0[ks].x - mean) * rs * gp_l[kb + 0] + bp_l[kb + 0]);
    a[ks][1] = (short)f2b((x0[ks].y - mean) * rs * gp_l[kb + 1] + bp_l[kb + 1]);
    a[ks][2] = (short)f2b((x0[ks].z - mean) * rs * gp_l[kb + 2] + bp_l[kb + 2]);
    a[ks][3] = (short)f2b((x0[ks].w - mean) * rs * gp_l[kb + 3] + bp_l[kb + 3]);
    a[ks][4] = (short)f2b((x1[ks].x - mean) * rs * gp_l[kb + 4] + bp_l[kb + 4]);
    a[ks][5] = (short)f2b((x1[ks].y - mean) * rs * gp_l[kb + 5] + bp_l[kb + 5]);
    a[ks][6] = (short)f2b((x1[ks].z - mean) * rs * gp_l[kb + 6] + bp_l[kb + 6]);
    a[ks][7] = (short)f2b((x1[ks].w - mean) * rs * gp_l[kb + 7] + bp_l[kb + 7]);
  }

  float bj4[4], gn4[4], bn4[4];
  #pragma unroll
  for (int nt = 0; nt < 4; ++nt) {
    int col = nt * 16 + r16;
    bj4[nt] = bproj[col]; gn4[nt] = gin[col]; bn4[nt] = bin[col];
  }

  f32x4v acc[4];
  #pragma unroll
  for (int nt = 0; nt < 4; ++nt)
    #pragma unroll
    for (int i = 0; i < 4; ++i) acc[nt][i] = 0.f;
  #define LDWP(ks, nt) \
    (*(const short8*)((const char*)wp_sw + \
        ((((nt) * 16 + r16) * 512 + 64 * (ks) + 16 * q4) ^ (((r16) & 7) << 4))))
  short8 b0 = LDWP(0, 0), b1 = LDWP(0, 1), b2f_ = LDWP(0, 2), b3 = LDWP(0, 3);
  #pragma unroll
  for (int ks = 0; ks < 8; ++ks) {
    short8 n0, n1, n2, n3;
    if (ks < 7) { n0 = LDWP(ks + 1, 0); n1 = LDWP(ks + 1, 1);
                  n2 = LDWP(ks + 1, 2); n3 = LDWP(ks + 1, 3); }
    acc[0] = __builtin_amdgcn_mfma_f32_16x16x32_bf16(a[ks], b0, acc[0], 0, 0, 0);
    acc[1] = __builtin_amdgcn_mfma_f32_16x16x32_bf16(a[ks], b1, acc[1], 0, 0, 0);
    acc[2] = __builtin_amdgcn_mfma_f32_16x16x32_bf16(a[ks], b2f_, acc[2], 0, 0, 0);
    acc[3] = __builtin_amdgcn_mfma_f32_16x16x32_bf16(a[ks], b3, acc[3], 0, 0, 0);
    b0 = n0; b1 = n1; b2f_ = n2; b3 = n3;
  }
  #undef LDWP
  #pragma unroll
  for (int nt = 0; nt < 4; ++nt)
    #pragma unroll
    for (int reg = 0; reg < 4; ++reg) acc[nt][reg] += bj4[nt];

  #pragma unroll
  for (int reg = 0; reg < 4; ++reg) {
    float s = acc[0][reg] + acc[1][reg] + acc[2][reg] + acc[3][reg];
    float q2 = acc[0][reg] * acc[0][reg] + acc[1][reg] * acc[1][reg] +
               acc[2][reg] * acc[2][reg] + acc[3][reg] * acc[3][reg];
    #pragma unroll
    for (int m = 1; m < 16; m <<= 1) { s += __shfl_xor(s, m); q2 += __shfl_xor(q2, m); }
    float mn = s * (1.f / 64.f);
    float rr = rsqrtf(q2 * (1.f / 64.f) - mn * mn + LNEPS);
    int row = q4 * 4 + reg;
    int rowg = w * 16 + row;
    #pragma unroll
    for (int nt = 0; nt < 4; ++nt) {
      int col = nt * 16 + r16;
      float y = (acc[nt][reg] - mn) * rr * gn4[nt] + bn4[nt];
      int byte = (rowg * 128 + 2 * col) ^ ((row & 7) << 4);
      *(u16*)((char*)xn_lds + byte) = f2b(y);
    }
  }

  f32x4v kacc[4], vacc[4];
  #pragma unroll
  for (int nt = 0; nt < 4; ++nt)
    #pragma unroll
    for (int i = 0; i < 4; ++i) { kacc[nt][i] = 0.f; vacc[nt][i] = 0.f; }
  #pragma unroll
  for (int ks = 0; ks < 2; ++ks) {
    int rowg2 = w * 16 + r16;
    short8 af = *(const short8*)((const char*)xn_lds +
                                 ((rowg2 * 128 + 64 * ks + 16 * q4) ^ ((r16 & 7) << 4)));
    #pragma unroll
    for (int nt = 0; nt < 4; ++nt) {
      int n = nt * 16 + r16;
      int wb = (n * 128 + 64 * ks + 16 * q4) ^ ((n & 7) << 4);
      short8 bk = *(const short8*)((const char*)wk_sw + wb);
      short8 bv = *(const short8*)((const char*)wv_sw + wb);
      kacc[nt] = __builtin_amdgcn_mfma_f32_16x16x32_bf16(af, bk, kacc[nt], 0, 0, 0);
      vacc[nt] = __builtin_amdgcn_mfma_f32_16x16x32_bf16(af, bv, vacc[nt], 0, 0, 0);
    }
  }
  #pragma unroll
  for (int nt = 0; nt < 4; ++nt) {
    #pragma unroll
    for (int reg = 0; reg < 4; ++reg) {
      int row = q4 * 4 + reg;
      long gr = rowbase + row;
      int col = nt * 16 + r16;
      long tile = gr >> 7;               // k: per-128-row swizzle image
      int  r    = (int)(gr & 127);
      long ko = tile * 8192 + ((r * 64 + col) ^ ((r & 7) << 3));
      k_ws[ko] = f2b(kacc[nt][reg]);
      v_ws[gr * 64 + col] = f2b(vacc[nt][reg]);
    }
  }
}

// ---------------------------------------------------------------------------
// K2: pure attention stream. grid (32,32), 128 thr. Stage 16KB k-tile via
// gll16 ∥ load 2KB q; logits; softmax; PV (v direct); partials out.
// ---------------------------------------------------------------------------
__global__ __launch_bounds__(128) void k_attn(
    const float* __restrict__ q_ws, const u16* __restrict__ k_img,
    const u16* __restrict__ v_ws, float* __restrict__ S_part,
    float* __restrict__ U_part) {
  const int bx = blockIdx.x, by = blockIdx.y, t = threadIdx.x;
  const int l = t & 63, w = t >> 6;
  __shared__ __align__(16) u16 k_l[8192];        // 16KB swizzle tile
  __shared__ float ql[512];
  __shared__ __align__(16) float attn_l[1024];   // reused as ured
  __shared__ float sred[16];

  {
    const char* gsrc = (const char*)(k_img + ((long)(by * 32 + bx)) * 8192);
    #pragma unroll
    for (int i = 0; i < 8; ++i) {
      int off = i * 2048 + t * 16;
      gll16(gsrc + off, (char*)k_l + off);
    }
  }
  for (int i = t; i < 512; i += 128) ql[i] = q_ws[by * 512 + i];
  __syncthreads();   // q in LDS + k staged (barrier drains vmcnt)

  // logits for n = bx*128 + t (row t of tile)
  short8 kw8[8];
  #pragma unroll
  for (int j = 0; j < 8; ++j)
    kw8[j] = *(const short8*)((const char*)k_l + ((t * 128 + 16 * j) ^ ((t & 7) << 4)));
  float lg[8];
  #pragma unroll
  for (int i = 0; i < 8; ++i) lg[i] = 0.f;
  #pragma unroll
  for (int c4 = 0; c4 < 16; ++c4) {
    int j = c4 >> 1, e0 = (c4 & 1) * 4;
    float f0 = b2f((u16)kw8[j][e0]);
    float f1 = b2f((u16)kw8[j][e0 + 1]);
    float f2v = b2f((u16)kw8[j][e0 + 2]);
    float f3 = b2f((u16)kw8[j][e0 + 3]);
    #pragma unroll
    for (int kk = 0; kk < 8; ++kk) {
      float4 qv = *(const float4*)(ql + kk * 64 + c4 * 4);
      lg[kk] += qv.x * f0 + qv.y * f1 + qv.z * f2v + qv.w * f3;
    }
  }
  float mx = lg[0];
  #pragma unroll
  for (int kk = 1; kk < 8; ++kk) mx = fmaxf(mx, lg[kk]);
  float e[8], ss = 0.f;
  #pragma unroll
  for (int kk = 0; kk < 8; ++kk) { e[kk] = __expf(lg[kk] - mx); ss += e[kk]; }
  float inv = 1.f / ss;
  #pragma unroll
  for (int kk = 0; kk < 8; ++kk) e[kk] *= inv;
  float4 A0 = {e[0], e[1], e[2], e[3]}, A1 = {e[4], e[5], e[6], e[7]};
  *(float4*)(attn_l + t * 8) = A0;
  *(float4*)(attn_l + t * 8 + 4) = A1;
  __syncthreads();

  // PV: wave w owns 64-n strip; lane owns d-pair p; v dense from L2/L3
  float au[8][2];
  #pragma unroll
  for (int i = 0; i < 8; ++i) { au[i][0] = 0.f; au[i][1] = 0.f; }
  const int p = l & 31, g = l >> 5;
  const u32* vw = (const u32*)(v_ws + ((long)by * Nn + bx * 128 + w * 64) * 64);
  #pragma unroll 8
  for (int nn = 0; nn < 32; ++nn) {
    int n = nn * 2 + g;
    float4 a0 = *(const float4*)(attn_l + (w * 64 + n) * 8);
    float4 a1 = *(const float4*)(attn_l + (w * 64 + n) * 8 + 4);
    u32 vv = vw[n * 32 + p];
    float vlo = b2f((u16)(vv & 0xffff)), vhi = b2f((u16)(vv >> 16));
    au[0][0] += a0.x * vlo; au[0][1] += a0.x * vhi;
    au[1][0] += a0.y * vlo; au[1][1] += a0.y * vhi;
    au[2][0] += a0.z * vlo; au[2][1] += a0.z * vhi;
    au[3][0] += a0.w * vlo; au[3][1] += a0.w * vhi;
    au[4][0] += a1.x * vlo; au[4][1] += a1.x * vhi;
    au[5][0] += a1.y * vlo; au[5][1] += a1.y * vhi;
    au[6][0] += a1.z * vlo; au[6][1] += a1.z * vhi;
    au[7][0] += a1.w * vlo; au[7][1] += a1.w * vhi;
  }
  #pragma unroll
  for (int kk = 0; kk < 8; ++kk) {
    au[kk][0] += __shfl_xor(au[kk][0], 32);
    au[kk][1] += __shfl_xor(au[kk][1], 32);
  }
  float s8[8];
  #pragma unroll
  for (int kk = 0; kk < 8; ++kk) {
    s8[kk] = e[kk];
    #pragma unroll
    for (int m = 1; m < 64; m <<= 1) s8[kk] += __shfl_xor(s8[kk], m);
  }
  __syncthreads();            // attn_l reads done -> reuse as ured
  float* ured = attn_l;
  if (l < 32) {
    #pragma unroll
    for (int kk = 0; kk < 8; ++kk) {
      ured[w * 512 + kk * 64 + 2 * p]     = au[kk][0];
      ured[w * 512 + kk * 64 + 2 * p + 1] = au[kk][1];
    }
  }
  if (l == 0) {
    #pragma unroll
    for (int kk = 0; kk < 8; ++kk) sred[w * 8 + kk] = s8[kk];
  }
  __syncthreads();
  for (int i = t; i < 512; i += 128)
    U_part[((long)(by * 32 + bx)) * 512 + i] = ured[i] + ured[512 + i];
  if (t < 8)
    S_part[(by * 32 + bx) * 8 + t] = sred[t] + sred[8 + t];
}

// ---------------------------------------------------------------------------
// K3: reduce partials, GRU, residual MLP -> slots; then LN+q -> q_ws.
// ---------------------------------------------------------------------------
__global__ __launch_bounds__(256) void k_update(
    const float* __restrict__ S_part, const float* __restrict__ U_part,
    const float* __restrict__ slots_in, int init_slots,
    const float* __restrict__ noise, const float* __restrict__ mu,
    const float* __restrict__ ls, const float* __restrict__ W_ih,
    const float* __restrict__ W_hh, const float* __restrict__ b_ih,
    const float* __restrict__ b_hh, const float* __restrict__ gm,
    const float* __restrict__ bm, const float* __restrict__ W1,
    const float* __restrict__ b1, const float* __restrict__ W2,
    const float* __restrict__ b2, const float* __restrict__ gs,
    const float* __restrict__ bs, const float* __restrict__ Wq,
    float* __restrict__ slots_out, float* __restrict__ q_ws,
    float* __restrict__ out_slots, int write_out) {
  const int b = blockIdx.x, t = threadIdx.x;
  __shared__ float u_l[512], sp[512], gi[1536], gh[1536], sn2[512], mi[512],
      h1[1024], Ssum[8];
  if (t < 8) {
    float s = 0.f;
    #pragma unroll
    for (int ch = 0; ch < 32; ++ch) s += S_part[(b * 32 + ch) * 8 + t];
    Ssum[t] = s;
  }
  for (int i = t; i < 512; i += 256) {
    float v;
    if (init_slots) { int d = i & 63; v = mu[d] + __expf(ls[d]) * noise[b * 512 + i]; }
    else v = slots_in[b * 512 + i];
    sp[i] = v;
  }
  __syncthreads();
  for (int i = t; i < 512; i += 256) {
    float s = 0.f;
    #pragma unroll
    for (int ch = 0; ch < 32; ++ch) s += U_part[((long)(b * 32 + ch)) * 512 + i];
    u_l[i] = s / (Ssum[i >> 6] + EPSc);
  }
  __syncthreads();
  for (int i = t; i < 1536; i += 256) {
    int kk = i / 192, j = i - kk * 192;
    gi[i] = b_ih[j] + dot64(u_l + kk * 64, W_ih + j * 64);
    gh[i] = b_hh[j] + dot64(sp + kk * 64, W_hh + j * 64);
  }
  __syncthreads();
  for (int i = t; i < 512; i += 256) {
    int kk = i >> 6, d = i & 63, base = kk * 192;
    float r = sigmoidf_(gi[base + d] + gh[base + d]);
    float z = sigmoidf_(gi[base + 64 + d] + gh[base + 64 + d]);
    float nn = tanhf(gi[base + 128 + d] + r * gh[base + 128 + d]);
    sn2[i] = (1.f - z) * nn + z * sp[i];
  }
  __syncthreads();
  ln8(sn2, mi, gm, bm, t);
  __syncthreads();
  for (int i = t; i < 1024; i += 256) {
    int kk = i >> 7, j = i & 127;
    h1[i] = fmaxf(b1[j] + dot64(mi + kk * 64, W1 + j * 64), 0.f);
  }
  __syncthreads();
  for (int i = t; i < 512; i += 256) {
    int kk = i >> 6, d = i & 63;
    float s = sn2[i] + b2[d] + dot128(h1 + kk * 128, W2 + d * 128);
    slots_out[b * 512 + i] = s;
    if (write_out) out_slots[b * 512 + i] = s;
    u_l[i] = s;
  }
  __syncthreads();
  ln8(u_l, mi, gs, bs, t);
  __syncthreads();
  for (int i = t; i < 512; i += 256)
    q_ws[b * 512 + i] = SCALEc * dot64(mi + (i >> 6) * 64, Wq + (i & 63) * 64);
}

// ---------------------------------------------------------------------------
// K4: final attention map. grid (32,32), 128 thr; q from q_ws; staged k.
// ---------------------------------------------------------------------------
__global__ __launch_bounds__(128) void k_final(
    const float* __restrict__ q_ws, const u16* __restrict__ k_img,
    float* __restrict__ outA) {
  const int bx = blockIdx.x, by = blockIdx.y, t = threadIdx.x;
  __shared__ __align__(16) u16 k_l[8192];
  __shared__ float ql[512];
  {
    const char* gsrc = (const char*)(k_img + ((long)(by * 32 + bx)) * 8192);
    #pragma unroll
    for (int i = 0; i < 8; ++i) {
      int off = i * 2048 + t * 16;
      gll16(gsrc + off, (char*)k_l + off);
    }
  }
  for (int i = t; i < 512; i += 128) ql[i] = q_ws[by * 512 + i];
  __syncthreads();
  short8 kw8[8];
  #pragma unroll
  for (int j = 0; j < 8; ++j)
    kw8[j] = *(const short8*)((const char*)k_l + ((t * 128 + 16 * j) ^ ((t & 7) << 4)));
  float lg[8];
  #pragma unroll
  for (int i = 0; i < 8; ++i) lg[i] = 0.f;
  #pragma unroll
  for (int c4 = 0; c4 < 16; ++c4) {
    int j = c4 >> 1, e0 = (c4 & 1) * 4;
    float f0 = b2f((u16)kw8[j][e0]);
    float f1 = b2f((u16)kw8[j][e0 + 1]);
    float f2v = b2f((u16)kw8[j][e0 + 2]);
    float f3 = b2f((u16)kw8[j][e0 + 3]);
    #pragma unroll
    for (int kk = 0; kk < 8; ++kk) {
      float4 qv = *(const float4*)(ql + kk * 64 + c4 * 4);
      lg[kk] += qv.x * f0 + qv.y * f1 + qv.z * f2v + qv.w * f3;
    }
  }
  float mx = lg[0];
  #pragma unroll
  for (int kk = 1; kk < 8; ++kk) mx = fmaxf(mx, lg[kk]);
  float e[8], ss = 0.f;
  #pragma unroll
  for (int kk = 0; kk < 8; ++kk) { e[kk] = __expf(lg[kk] - mx); ss += e[kk]; }
  float inv = 1.f / ss;
  int n = bx * 128 + t;
  #pragma unroll
  for (int kk = 0; kk < 8; ++kk)
    outA[((long)by * 8 + kk) * 4096 + n] = e[kk] * inv;
}

extern "C" void kernel_launch(void* const* d_in, const int* in_sizes, int n_in,
                              void* d_out, int out_size, void* d_ws, size_t ws_size,
                              hipStream_t stream) {
  (void)in_sizes; (void)n_in; (void)out_size; (void)ws_size;
  const float* in    = (const float*)d_in[0];
  const float* noise = (const float*)d_in[1];
  const float* mu    = (const float*)d_in[2];
  const float* ls    = (const float*)d_in[3];
  const float* gpro  = (const float*)d_in[4];
  const float* bpro  = (const float*)d_in[5];
  const float* Wp    = (const float*)d_in[6];
  const float* bproj = (const float*)d_in[7];
  const float* Wq    = (const float*)d_in[8];
  const float* Wk    = (const float*)d_in[9];
  const float* Wv    = (const float*)d_in[10];
  const float* W_ih  = (const float*)d_in[11];
  const float* W_hh  = (const float*)d_in[12];
  const float* b_ih  = (const float*)d_in[13];
  const float* b_hh  = (const float*)d_in[14];
  const float* W1    = (const float*)d_in[15];
  const float* b1    = (const float*)d_in[16];
  const float* W2    = (const float*)d_in[17];
  const float* b2    = (const float*)d_in[18];
  const float* gin   = (const float*)d_in[19];
  const float* bin   = (const float*)d_in[20];
  const float* gs    = (const float*)d_in[21];
  const float* bs    = (const float*)d_in[22];
  const float* gm    = (const float*)d_in[23];
  const float* bm    = (const float*)d_in[24];

  char* ws = (char*)d_ws;
  u16* k_ws      = (u16*)ws;                                   // 16 MiB swizzle image
  u16* v_ws      = (u16*)(ws + 16777216);                      // 16 MiB linear
  float* S_part  = (float*)(ws + 33554432);                    // 32 KiB
  float* U_part  = (float*)(ws + 33554432 + 32768);            // 2 MiB
  float* slots_a = (float*)(ws + 33554432 + 32768 + 2097152);  // 64 KiB
  float* slots_b = (float*)(ws + 33554432 + 32768 + 2097152 + 65536);
  float* q_ws    = (float*)(ws + 33554432 + 32768 + 2097152 + 131072);
  u16* wp_sw     = (u16*)(ws + 33554432 + 32768 + 2097152 + 131072 + 65536);
  u16* wk_sw     = wp_sw + 16384;
  u16* wv_sw     = wk_sw + 4096;
  float* out = (float*)d_out;

  k_prep<<<dim3(96), dim3(256), 0, stream>>>(Wp, Wk, Wv, wp_sw, wk_sw, wv_sw,
                                             noise, mu, ls, gs, bs, Wq, q_ws);
  k_proj_kv<<<dim3(2048), dim3(256), 0, stream>>>(in, gpro, bpro, wp_sw, bproj,
                                                  gin, bin, wk_sw, wv_sw, k_ws, v_ws);
  dim3 ga(32, 32), ba(128);
  // iter 0
  k_attn<<<ga, ba, 0, stream>>>(q_ws, k_ws, v_ws, S_part, U_part);
  k_update<<<dim3(32), dim3(256), 0, stream>>>(S_part, U_part, slots_a, 1, noise,
                                               mu, ls, W_ih, W_hh, b_ih, b_hh, gm,
                                               bm, W1, b1, W2, b2, gs, bs, Wq,
                                               slots_a, q_ws, out, 0);
  // iter 1
  k_attn<<<ga, ba, 0, stream>>>(q_ws, k_ws, v_ws, S_part, U_part);
  k_update<<<dim3(32), dim3(256), 0, stream>>>(S_part, U_part, slots_a, 0, noise,
                                               mu, ls, W_ih, W_hh, b_ih, b_hh, gm,
                                               bm, W1, b1, W2, b2, gs, bs, Wq,
                                               slots_b, q_ws, out, 0);
  // iter 2 (slots -> d_out)
  k_attn<<<ga, ba, 0, stream>>>(q_ws, k_ws, v_ws, S_part, U_part);
  k_update<<<dim3(32), dim3(256), 0, stream>>>(S_part, U_part, slots_b, 0, noise,
                                               mu, ls, W_ih, W_hh, b_ih, b_hh, gm,
                                               bm, W1, b1, W2, b2, gs, bs, Wq,
                                               slots_a, q_ws, out, 1);
  // final attention map
  k_final<<<ga, ba, 0, stream>>>(q_ws, k_ws, out + 16384);
}